// Round 3
// baseline (88.572 us; speedup 1.0000x reference)
//
#include <hip/hip_runtime.h>
#include <math.h>

#define BB 4
#define HH 512
#define WW 512
#define HWSZ (HH * WW)
#define NBLK 256                     // 4 batches x 64 blocks; == CU count (co-resident)

#define SK(x) ((x) + ((x) >> 5))     // LDS skew: 64 lanes -> 32 banks 2-way (free)

// ws layout (first 32 B zeroed by hipMemsetAsync before launch):
//   [0,  8)   double dacc        (global accumulator)
//   [8, 12)   u32 done           (ticket counter for final out write)
//   [12,16)   u32 flagword       (bit b = batch b has foreground)
//   [16,32)   u32 pdone[4]       (per-batch pack-arrival counters)
//   [32768, +128K) u32 cw[BB][16][512]  (bit i of cw[b][w][col] = mask at row 32w+i)

// ---------------------------------------------------------------------------
// Single fused kernel. Block blk: batch b = blk>>6, slice/row-group g = blk&63.
//   Phase 0: issue pred prefetch (float4 x4) -- in flight through pack+wait.
//   Phase 1 (pack): threads 0..127 each build one column-word (32 strided int
//            loads), store to cw, popc-reduce -> atomicOr presence bit.
//            syncthreads (drains stores) -> release fence -> pdone[b]++.
//            Thread 0 spins until pdone[b]==64 (all co-resident: grid==CUs,
//            66.5KB LDS/512thr -> 1 block/CU fits everywhere; no deadlock).
//            Acquire fence -> syncthreads -> batch mask fully visible.
//   Phase 2 (rows): identical to previous rows_kernel stages A/B/C.
//   Tail: block reduce -> presence-gated double atomicAdd -> ticket -> out.
// ---------------------------------------------------------------------------
__global__ __launch_bounds__(512) void fused_kernel(
    const int* __restrict__ target,
    const float* __restrict__ pred,
    unsigned int* __restrict__ cw,
    double* __restrict__ dacc,
    unsigned int* __restrict__ done,
    unsigned int* __restrict__ flagword,
    unsigned int* __restrict__ pdone,
    float* __restrict__ out)
{
    __shared__ unsigned int sW[16 * 512];                 // 32 KB
    __shared__ float g2n[8][SK(511) + 1], g2p[8][SK(511) + 1];  // ~33.8 KB
    __shared__ float wsum[8];
    __shared__ unsigned int sFW;

    int blk = blockIdx.x;
    int b = blk >> 6;
    int g = blk & 63;                // row group AND pack slice
    int tid = threadIdx.x;
    int w = tid >> 6, lane = tid & 63;
    int row = 8 * g + w;             // this wave's image row
    int j0 = 8 * lane;               // this lane's ring-search columns

    // ---- Phase 0: pred prefetch (consumed in stage C; overlaps pack+wait)
    const float* p0 = pred + (b * 2 + 0) * HWSZ + row * WW + j0;
    const float* p1 = pred + (b * 2 + 1) * HWSZ + row * WW + j0;
    float4 a0 = *(const float4*)(p0);
    float4 a1 = *(const float4*)(p0 + 4);
    float4 c0 = *(const float4*)(p1);
    float4 c1 = *(const float4*)(p1 + 4);

    // ---- Phase 1: pack this block's 128 column-words of batch b
    if (tid < 128) {
        int idx = (g << 7) + tid;         // word index within batch (0..8191)
        int wr = idx >> 9;                // word-row 0..15
        int col = idx & 511;
        const int* t = target + b * HWSZ + (wr << 5) * WW + col;
        unsigned int word = 0;
#pragma unroll
        for (int i = 0; i < 32; ++i)
            word |= (unsigned int)(t[i * WW] == 1) << i;
        cw[b * 8192 + idx] = word;
        int cnt = __popc(word);
#pragma unroll
        for (int off = 32; off > 0; off >>= 1) cnt += __shfl_down(cnt, off, 64);
        if (lane == 0 && cnt > 0) atomicOr(flagword, 1u << b);
    }
    __syncthreads();                      // drains this block's cw stores (vmcnt)
    if (tid == 0) {
        __threadfence();                  // release: XCD L2 writeback
        atomicAdd(&pdone[b], 1u);
        while (atomicAdd(&pdone[b], 0u) < 64u)
            __builtin_amdgcn_s_sleep(2);
        __threadfence();                  // acquire: invalidate stale lines
        sFW = atomicOr(flagword, 0u);     // presence bits (all producers fenced)
    }
    __syncthreads();                      // batch b's cw fully visible to block

    // ---- Stage A: batch mask -> LDS (coalesced, 4x uint4/thread)
    const uint4* cw4 = (const uint4*)(cw + b * 8192);
    uint4* sW4 = (uint4*)sW;
#pragma unroll
    for (int t = 0; t < 4; ++t)
        sW4[tid + 512 * t] = cw4[tid + 512 * t];
    __syncthreads();

    // ---- Stage B: build this row's g2n/g2p (lane covers cols lane+64t)
    int wr = row >> 5, bit = row & 31;
    float* G2N = g2n[w];
    float* G2P = g2p[w];
    unsigned int loMask = 0xFFFFFFFFu >> (31 - bit);   // bits 0..bit
    unsigned int hiMask = 0xFFFFFFFFu << bit;          // bits bit..31
#pragma unroll
    for (int t = 0; t < 8; ++t) {
        int col = lane + (t << 6);
        unsigned int Wr = sW[(wr << 9) + col];
        // --- N map (seed = mask)
        int dUp, dDn;
        unsigned int m = Wr & loMask;
        if (m) dUp = bit - (31 - __builtin_clz(m));
        else {
            dUp = 0x7FFFFFFF;
            for (int q = wr - 1; q >= 0; --q) {
                unsigned int W = sW[(q << 9) + col];
                if (W) { dUp = row - ((q << 5) + 31 - __builtin_clz(W)); break; }
            }
        }
        m = Wr & hiMask;
        if (m) dDn = __builtin_ctz(m) - bit;
        else {
            dDn = 0x7FFFFFFF;
            for (int q = wr + 1; q < 16; ++q) {
                unsigned int W = sW[(q << 9) + col];
                if (W) { dDn = (q << 5) + __builtin_ctz(W) - row; break; }
            }
        }
        int gN = min(dUp, dDn);
        G2N[SK(col)] = (gN > 511) ? 1e18f : (float)(gN * gN);
        // --- P map (seed = ~mask)
        unsigned int Vr = ~Wr;
        m = Vr & loMask;
        if (m) dUp = bit - (31 - __builtin_clz(m));
        else {
            dUp = 0x7FFFFFFF;
            for (int q = wr - 1; q >= 0; --q) {
                unsigned int W = ~sW[(q << 9) + col];
                if (W) { dUp = row - ((q << 5) + 31 - __builtin_clz(W)); break; }
            }
        }
        m = Vr & hiMask;
        if (m) dDn = __builtin_ctz(m) - bit;
        else {
            dDn = 0x7FFFFFFF;
            for (int q = wr + 1; q < 16; ++q) {
                unsigned int W = ~sW[(q << 9) + col];
                if (W) { dDn = (q << 5) + __builtin_ctz(W) - row; break; }
            }
        }
        int gP = min(dUp, dDn);
        G2P[SK(col)] = (gP > 511) ? 1e18f : (float)(gP * gP);
    }
    // G2N/G2P are wave-private and wave-coherent: no barrier needed.

    // ---- Stage C: sign-select ring search (exact)
    const float* sel[8];
    float bs[8], sgn[8];
#pragma unroll
    for (int jj = 0; jj < 8; ++jj) {
        float on = G2N[SK(j0 + jj)];
        float op = G2P[SK(j0 + jj)];
        bool fg = (on == 0.0f);      // fg pixel -> neg_dist = 0, search pos
        sel[jj] = fg ? G2P : G2N;
        bs[jj]  = fg ? op : on;
        sgn[jj] = fg ? -1.0f : 1.0f; // dmap = neg - pos
    }
    for (int r = 1; r < WW; ++r) {
        float sq = (float)(r * r);
        float mx = 0.0f;
#pragma unroll
        for (int jj = 0; jj < 8; ++jj) mx = fmaxf(mx, bs[jj]);
        if (sq >= mx) break;         // exact early exit
#pragma unroll
        for (int jj = 0; jj < 8; ++jj) {
            int kl = j0 + jj - r; kl = kl < 0 ? 0 : kl;
            int kr = j0 + jj + r; kr = kr > (WW - 1) ? (WW - 1) : kr;
            bs[jj] = fminf(bs[jj], sq + sel[jj][SK(kl)]);
            bs[jj] = fminf(bs[jj], sq + sel[jj][SK(kr)]);
        }
    }

    float x0[8] = {a0.x, a0.y, a0.z, a0.w, a1.x, a1.y, a1.z, a1.w};
    float x1[8] = {c0.x, c0.y, c0.z, c0.w, c1.x, c1.y, c1.z, c1.w};
    float acc = 0.0f;
#pragma unroll
    for (int jj = 0; jj < 8; ++jj) {
        float dist = sgn[jj] * sqrtf(bs[jj]);                  // negEDT - posEDT
        float prob = 1.0f / (1.0f + __expf(x0[jj] - x1[jj]));  // softmax class-1
        acc += prob * dist;
    }
#pragma unroll
    for (int off = 32; off > 0; off >>= 1) acc += __shfl_down(acc, off, 64);

    // ---- fused finalize: block reduce -> one double atomic -> last-block out
    if (lane == 0) wsum[w] = acc;
    __syncthreads();
    if (tid == 0) {
        double s = 0.0;
#pragma unroll
        for (int i = 0; i < 8; ++i) s += (double)wsum[i];
        if ((sFW >> b) & 1u) atomicAdd(dacc, s);  // presence guard ('mask.sum()>0')
        __threadfence();                          // order dacc add before ticket
        unsigned int t = atomicAdd(done, 1u);
        if (t == NBLK - 1) {
            double tot = atomicAdd(dacc, 0.0);    // coherent read of final sum
            out[0] = (float)(tot * (1.0 / 2097152.0));  // mean over B*C*H*W
        }
    }
}

extern "C" void kernel_launch(void* const* d_in, const int* in_sizes, int n_in,
                              void* d_out, int out_size, void* d_ws, size_t ws_size,
                              hipStream_t stream) {
    const float* pred = (const float*)d_in[0];
    const int* target = (const int*)d_in[1];
    float* out = (float*)d_out;

    char* ws = (char*)d_ws;
    double* dacc = (double*)(ws + 0);
    unsigned int* done = (unsigned int*)(ws + 8);
    unsigned int* flagword = (unsigned int*)(ws + 12);
    unsigned int* pdone = (unsigned int*)(ws + 16);
    unsigned int* cw = (unsigned int*)(ws + 32768);

    hipMemsetAsync(ws, 0, 32, stream);   // zero dacc/done/flagword/pdone
    fused_kernel<<<NBLK, 512, 0, stream>>>(target, pred, cw, dacc, done,
                                           flagword, pdone, out);
}

// Round 4
// 71.969 us; speedup vs baseline: 1.2307x; 1.2307x over previous
//
#include <hip/hip_runtime.h>
#include <math.h>

#define BB 4
#define HH 512
#define WW 512
#define HWSZ (HH * WW)
#define ROWS_BLOCKS 256              // 4 batches x 64 row-groups (8 rows each)

#define SK(x) ((x) + ((x) >> 5))     // LDS skew: 64 lanes -> 32 banks 2-way (free)

// ws layout:
//   [0,    512)    int flags[128]       (per pack-block: batch-slice has fg)
//   [1024, 9216)   float partials[2048] (one per row; all written by rows)
//   [32768, +128K) u32 cw[BB][16][512]  (bit i of cw[b][w][col] = mask at row 32w+i)

// ---------------------------------------------------------------------------
// Pass 1: bit-pack the target mask into column words. Thread (b,w,col) reads
// 32 ints down a column (independent loads, lane-consecutive cols = coalesced
// 256B lines) -> one u32. Presence flag per block via popc wave-reduce
// (layout: 32 blocks per batch, matching finalize's ballot).
// ---------------------------------------------------------------------------
__global__ __launch_bounds__(256) void pack_kernel(
    const int* __restrict__ target,
    unsigned int* __restrict__ cw,
    int* __restrict__ flags)
{
    __shared__ int sCnt;
    int gid = blockIdx.x * 256 + threadIdx.x;   // 0..32767
    int b = gid >> 13;
    int rem = gid & 8191;
    int w = rem >> 9;                // word-row 0..15
    int col = rem & 511;

    const int* t = target + b * HWSZ + (w << 5) * WW + col;
    unsigned int word = 0;
#pragma unroll
    for (int i = 0; i < 32; ++i)
        word |= (unsigned int)(t[i * WW] == 1) << i;
    cw[gid] = word;

    int cnt = __popc(word);
#pragma unroll
    for (int off = 32; off > 0; off >>= 1) cnt += __shfl_down(cnt, off, 64);
    if (threadIdx.x == 0) sCnt = 0;
    __syncthreads();
    if ((threadIdx.x & 63) == 0) atomicAdd(&sCnt, cnt);
    __syncthreads();
    if (threadIdx.x == 0) flags[blockIdx.x] = (sCnt > 0);
}

// ---------------------------------------------------------------------------
// Pass 2: 8 rows per block (one per wave). Stage A: load the batch's full
// 32 KB column-word mask into LDS. Stage B: exact per-(row,col) column
// distances gN,gP via clz/ctz on the own word + outward word loop (first
// word hits on dense data; loop keeps worst-case exact). Build per-wave
// g2n/g2p rows in LDS (stride-64 cols -> conflict-free). Stage C: R8's
// sign-select expanding-ring search (exactly one of neg/pos dist is zero
// per pixel -> search one map, emit +/-sqrt; clamped edges over-estimate
// only -> exact), sigmoid weighting, 6-shuffle reduce, one f32 per row.
// ---------------------------------------------------------------------------
__global__ __launch_bounds__(512) void rows_kernel(
    const unsigned int* __restrict__ cw,
    const float* __restrict__ pred,
    float* __restrict__ partials)
{
    __shared__ unsigned int sW[16 * 512];                 // 32 KB
    __shared__ float g2n[8][SK(511) + 1], g2p[8][SK(511) + 1];  // ~33.8 KB

    int blk = blockIdx.x;
    int b = blk >> 6;
    int g = blk & 63;                // row group
    int tid = threadIdx.x;
    int w = tid >> 6, lane = tid & 63;
    int row = 8 * g + w;             // this wave's image row
    int j0 = 8 * lane;               // this lane's ring-search columns

    // pred loads issued first (consumed in stage C)
    const float* p0 = pred + (b * 2 + 0) * HWSZ + row * WW + j0;
    const float* p1 = pred + (b * 2 + 1) * HWSZ + row * WW + j0;
    float4 a0 = *(const float4*)(p0);
    float4 a1 = *(const float4*)(p0 + 4);
    float4 c0 = *(const float4*)(p1);
    float4 c1 = *(const float4*)(p1 + 4);

    // ---- Stage A: batch mask -> LDS (coalesced, 16 words/thread)
    const unsigned int* cwb = cw + b * 8192;
#pragma unroll
    for (int t = 0; t < 16; ++t)
        sW[tid + 512 * t] = cwb[tid + 512 * t];
    __syncthreads();

    // ---- Stage B: build this row's g2n/g2p (lane covers cols lane+64t)
    int wr = row >> 5, bit = row & 31;
    float* G2N = g2n[w];
    float* G2P = g2p[w];
    unsigned int loMask = 0xFFFFFFFFu >> (31 - bit);   // bits 0..bit
    unsigned int hiMask = 0xFFFFFFFFu << bit;          // bits bit..31
#pragma unroll
    for (int t = 0; t < 8; ++t) {
        int col = lane + (t << 6);
        unsigned int Wr = sW[(wr << 9) + col];
        // --- N map (seed = mask)
        int dUp, dDn;
        unsigned int m = Wr & loMask;
        if (m) dUp = bit - (31 - __builtin_clz(m));
        else {
            dUp = 0x7FFFFFFF;
            for (int q = wr - 1; q >= 0; --q) {
                unsigned int W = sW[(q << 9) + col];
                if (W) { dUp = row - ((q << 5) + 31 - __builtin_clz(W)); break; }
            }
        }
        m = Wr & hiMask;
        if (m) dDn = __builtin_ctz(m) - bit;
        else {
            dDn = 0x7FFFFFFF;
            for (int q = wr + 1; q < 16; ++q) {
                unsigned int W = sW[(q << 9) + col];
                if (W) { dDn = (q << 5) + __builtin_ctz(W) - row; break; }
            }
        }
        int gN = min(dUp, dDn);
        G2N[SK(col)] = (gN > 511) ? 1e18f : (float)(gN * gN);
        // --- P map (seed = ~mask)
        unsigned int Vr = ~Wr;
        m = Vr & loMask;
        if (m) dUp = bit - (31 - __builtin_clz(m));
        else {
            dUp = 0x7FFFFFFF;
            for (int q = wr - 1; q >= 0; --q) {
                unsigned int W = ~sW[(q << 9) + col];
                if (W) { dUp = row - ((q << 5) + 31 - __builtin_clz(W)); break; }
            }
        }
        m = Vr & hiMask;
        if (m) dDn = __builtin_ctz(m) - bit;
        else {
            dDn = 0x7FFFFFFF;
            for (int q = wr + 1; q < 16; ++q) {
                unsigned int W = ~sW[(q << 9) + col];
                if (W) { dDn = (q << 5) + __builtin_ctz(W) - row; break; }
            }
        }
        int gP = min(dUp, dDn);
        G2P[SK(col)] = (gP > 511) ? 1e18f : (float)(gP * gP);
    }
    // G2N/G2P are wave-private and wave-coherent: no barrier needed.

    // ---- Stage C: sign-select ring search (R8-proven exact)
    const float* sel[8];
    float bs[8], sgn[8];
#pragma unroll
    for (int jj = 0; jj < 8; ++jj) {
        float on = G2N[SK(j0 + jj)];
        float op = G2P[SK(j0 + jj)];
        bool fg = (on == 0.0f);      // fg pixel -> neg_dist = 0, search pos
        sel[jj] = fg ? G2P : G2N;
        bs[jj]  = fg ? op : on;
        sgn[jj] = fg ? -1.0f : 1.0f; // dmap = neg - pos
    }
    for (int r = 1; r < WW; ++r) {
        float sq = (float)(r * r);
        float mx = 0.0f;
#pragma unroll
        for (int jj = 0; jj < 8; ++jj) mx = fmaxf(mx, bs[jj]);
        if (sq >= mx) break;         // exact early exit
#pragma unroll
        for (int jj = 0; jj < 8; ++jj) {
            int kl = j0 + jj - r; kl = kl < 0 ? 0 : kl;
            int kr = j0 + jj + r; kr = kr > (WW - 1) ? (WW - 1) : kr;
            bs[jj] = fminf(bs[jj], sq + sel[jj][SK(kl)]);
            bs[jj] = fminf(bs[jj], sq + sel[jj][SK(kr)]);
        }
    }

    float x0[8] = {a0.x, a0.y, a0.z, a0.w, a1.x, a1.y, a1.z, a1.w};
    float x1[8] = {c0.x, c0.y, c0.z, c0.w, c1.x, c1.y, c1.z, c1.w};
    float acc = 0.0f;
#pragma unroll
    for (int jj = 0; jj < 8; ++jj) {
        float dist = sgn[jj] * sqrtf(bs[jj]);                  // negEDT - posEDT
        float prob = 1.0f / (1.0f + __expf(x0[jj] - x1[jj]));  // softmax class-1
        acc += prob * dist;
    }
#pragma unroll
    for (int off = 32; off > 0; off >>= 1) acc += __shfl_down(acc, off, 64);
    if (lane == 0) partials[b * HH + row] = acc;
}

// ---------------------------------------------------------------------------
// Pass 3 (unchanged): single wave. 8x float4 partial loads per lane, per-batch
// presence guard via 4 ballots over the 32 pack-block flags, double reduce.
// ---------------------------------------------------------------------------
__global__ __launch_bounds__(64) void finalize_kernel(
    const int* __restrict__ flags,
    const float* __restrict__ partials,
    float* __restrict__ out)
{
    int k = threadIdx.x;

    double presd[BB];
#pragma unroll
    for (int b = 0; b < BB; ++b) {
        int f = (k < 32) ? flags[b * 32 + k] : 0;
        presd[b] = (__ballot(f != 0) != 0ULL) ? 1.0 : 0.0;  // 'mask.sum()>0'
    }

    const float4* p4 = (const float4*)partials;
    double s = 0.0;
#pragma unroll
    for (int t = 0; t < 8; ++t) {
        int v4 = k + 64 * t;                 // float4 index 0..511
        float4 v = p4[v4];
        double gd = presd[v4 >> 7];          // batch = (4*v4)>>9
        s += gd * ((double)v.x + (double)v.y + (double)v.z + (double)v.w);
    }
#pragma unroll
    for (int off = 32; off > 0; off >>= 1) s += __shfl_down(s, off, 64);
    if (k == 0)
        out[0] = (float)(s * (1.0 / 2097152.0));   // mean over B*C*H*W
}

extern "C" void kernel_launch(void* const* d_in, const int* in_sizes, int n_in,
                              void* d_out, int out_size, void* d_ws, size_t ws_size,
                              hipStream_t stream) {
    const float* pred = (const float*)d_in[0];
    const int* target = (const int*)d_in[1];
    float* out = (float*)d_out;

    char* ws = (char*)d_ws;
    int* flags = (int*)(ws + 0);
    float* partials = (float*)(ws + 1024);
    unsigned int* cw = (unsigned int*)(ws + 32768);

    pack_kernel<<<128, 256, 0, stream>>>(target, cw, flags);
    rows_kernel<<<ROWS_BLOCKS, 512, 0, stream>>>(cw, pred, partials);
    finalize_kernel<<<1, 64, 0, stream>>>(flags, partials, out);
}